// Round 1
// baseline (111.618 us; speedup 1.0000x reference)
//
#include <hip/hip_runtime.h>
#include <hip/hip_bf16.h>

#define NTOT 8192
#define NBSZ 4096
#define DDIM 256
#define NCHUNK 8
#define CHUNK_COLS 1024
#define ROWS_PER_BLK 128
#define TILE_COLS 64

#define INV_T 14.285714285714286f   /* 1/0.07 */
#define EPI_T 1.4285714285714286f   /* 0.1/0.07 (sq_i == 1 to fp32 roundoff) */

typedef __attribute__((ext_vector_type(8))) __bf16 bf16x8;
typedef __attribute__((ext_vector_type(4))) float f32x4;

__device__ __forceinline__ unsigned short f2bf(float x) {
    union { float f; unsigned int u; } a; a.f = x;
    unsigned int r = a.u + 0x7fffu + ((a.u >> 16) & 1u);
    return (unsigned short)(r >> 16);
}

// Build bf16 contrast matrix B[8192][256] (view-major) + tiled labels.
__global__ __launch_bounds__(64) void prep_kernel(const float* __restrict__ feat,
                                                  const int* __restrict__ labels,
                                                  unsigned short* __restrict__ Bg,
                                                  int* __restrict__ labT) {
    const int row = blockIdx.x;            // 0..8191
    const int v = row >> 12;               // row / 4096
    const int b = row & (NBSZ - 1);
    const float* src = feat + ((size_t)(b * 2 + v)) * DDIM;
    const int t = threadIdx.x;             // 64 threads, 4 cols each
    f32x4 val = *(const f32x4*)(src + t * 4);
    ushort4 o;
    o.x = f2bf(val[0]); o.y = f2bf(val[1]); o.z = f2bf(val[2]); o.w = f2bf(val[3]);
    *(ushort4*)(Bg + (size_t)row * DDIM + t * 4) = o;
    if (t == 0) labT[row] = labels[b];
}

// Fused Gram + online row-stats. Grid: (64 row-blocks, 8 col-chunks), 256 thr.
__global__ __launch_bounds__(256, 2) void supcon_main(
    const unsigned short* __restrict__ Bg, const int* __restrict__ labT,
    float* __restrict__ pM, float* __restrict__ pS,
    float* __restrict__ pP, float* __restrict__ pC)
{
    __shared__ unsigned short btile[TILE_COLS * DDIM];  // 32 KB, 16B-chunk XOR swizzle
    __shared__ int labc_s[TILE_COLS];

    const int tid = threadIdx.x;
    const int wid = tid >> 6;
    const int lane = tid & 63;
    const int q = lane >> 4;       // 0..3
    const int r16 = lane & 15;     // 0..15

    const int rowBase = blockIdx.x * ROWS_PER_BLK + wid * 32;
    const int colChunkBase = blockIdx.y * CHUNK_COLS;

    // A fragments for this wave's 32 rows, whole K=256, kept in registers.
    // mfma_f32_16x16x32_bf16 A layout: lane holds row (l&15), k = (l>>4)*8 + j.
    bf16x8 afr[2][8];
    #pragma unroll
    for (int m = 0; m < 2; ++m) {
        const unsigned short* arow = Bg + (size_t)(rowBase + m * 16 + r16) * DDIM + q * 8;
        #pragma unroll
        for (int ks = 0; ks < 8; ++ks)
            afr[m][ks] = *(const bf16x8*)(arow + ks * 32);
    }
    int labrow[2][4];
    #pragma unroll
    for (int m = 0; m < 2; ++m)
        #pragma unroll
        for (int r = 0; r < 4; ++r)
            labrow[m][r] = labT[rowBase + m * 16 + q * 4 + r];

    float mx[2][4], se[2][4], ps[2][4], pc[2][4];
    #pragma unroll
    for (int m = 0; m < 2; ++m)
        #pragma unroll
        for (int r = 0; r < 4; ++r) { mx[m][r] = -1e30f; se[m][r] = 0.f; ps[m][r] = 0.f; pc[m][r] = 0.f; }

    for (int tile = 0; tile < CHUNK_COLS / TILE_COLS; ++tile) {
        const int colBase = colChunkBase + tile * TILE_COLS;
        __syncthreads();  // protect LDS from previous tile's readers
        // Stage B tile [64][256] bf16: 2048 x 16B chunks, swizzle chunk ^= (row&7).
        #pragma unroll
        for (int it = 0; it < 8; ++it) {
            int idx = it * 256 + tid;      // 0..2047
            int brow = idx >> 5;           // 32 chunks per row
            int bc = idx & 31;
            bf16x8 vsrc = *(const bf16x8*)(Bg + (size_t)(colBase + brow) * DDIM + bc * 8);
            int dc = bc ^ (brow & 7);
            *(bf16x8*)(btile + brow * DDIM + dc * 8) = vsrc;
        }
        if (tid < TILE_COLS) labc_s[tid] = labT[colBase + tid];
        __syncthreads();

        f32x4 acc[2][4];
        #pragma unroll
        for (int m = 0; m < 2; ++m)
            #pragma unroll
            for (int n = 0; n < 4; ++n) acc[m][n] = (f32x4)0.f;

        #pragma unroll
        for (int ks = 0; ks < 8; ++ks) {
            bf16x8 bq[4];
            #pragma unroll
            for (int n = 0; n < 4; ++n) {
                int brow = n * 16 + r16;                 // B-operand col = matrix row
                int c = (ks * 4 + q) ^ (brow & 7);       // swizzled 16B chunk
                bq[n] = *(const bf16x8*)(btile + brow * DDIM + c * 8);
            }
            #pragma unroll
            for (int m = 0; m < 2; ++m)
                #pragma unroll
                for (int n = 0; n < 4; ++n)
                    acc[m][n] = __builtin_amdgcn_mfma_f32_16x16x32_bf16(afr[m][ks], bq[n], acc[m][n], 0, 0, 0);
        }

        // Fused epilogue: online (max, sumexp) + positive sums, all in registers.
        #pragma unroll
        for (int n = 0; n < 4; ++n) {
            const int gcol = colBase + n * 16 + r16;
            const int lc = labc_s[n * 16 + r16];
            #pragma unroll
            for (int m = 0; m < 2; ++m) {
                #pragma unroll
                for (int r = 0; r < 4; ++r) {
                    const int grow = rowBase + m * 16 + q * 4 + r;
                    const bool same = (lc == labrow[m][r]);
                    float logit = acc[m][n][r] * INV_T - (same ? EPI_T : 0.f);
                    const bool diag = (grow == gcol);
                    float e;
                    if (logit > mx[m][r]) {              // rare after first tiles
                        se[m][r] *= __expf(mx[m][r] - logit);
                        mx[m][r] = logit;
                        e = 1.f;
                    } else {
                        e = __expf(logit - mx[m][r]);
                    }
                    if (!diag) {
                        se[m][r] += e;
                        if (same) { ps[m][r] += logit; pc[m][r] += 1.f; }
                    }
                }
            }
        }
    }

    // Merge across the 16 lanes (bits 0..3) that share each output row.
    #pragma unroll
    for (int mask = 1; mask <= 8; mask <<= 1) {
        #pragma unroll
        for (int m = 0; m < 2; ++m)
            #pragma unroll
            for (int r = 0; r < 4; ++r) {
                float om = __shfl_xor(mx[m][r], mask);
                float os = __shfl_xor(se[m][r], mask);
                float nm = fmaxf(mx[m][r], om);
                se[m][r] = se[m][r] * __expf(mx[m][r] - nm) + os * __expf(om - nm);
                mx[m][r] = nm;
                ps[m][r] += __shfl_xor(ps[m][r], mask);
                pc[m][r] += __shfl_xor(pc[m][r], mask);
            }
    }
    if (r16 == 0) {
        const int ch = blockIdx.y;
        #pragma unroll
        for (int m = 0; m < 2; ++m)
            #pragma unroll
            for (int r = 0; r < 4; ++r) {
                int row = rowBase + m * 16 + q * 4 + r;
                size_t o = (size_t)ch * NTOT + row;
                pM[o] = mx[m][r]; pS[o] = se[m][r]; pP[o] = ps[m][r]; pC[o] = pc[m][r];
            }
    }
}

__global__ __launch_bounds__(1024) void finalize_kernel(
    const float* __restrict__ pM, const float* __restrict__ pS,
    const float* __restrict__ pP, const float* __restrict__ pC,
    float* __restrict__ out)
{
    const int t = threadIdx.x;
    float local = 0.f;
    for (int row = t; row < NTOT; row += 1024) {
        float m = -1e30f, S = 0.f, P = 0.f, C = 0.f;
        #pragma unroll
        for (int ch = 0; ch < NCHUNK; ++ch) {
            size_t o = (size_t)ch * NTOT + row;
            float cm = pM[o], cs = pS[o];
            float nm = fmaxf(m, cm);
            S = S * __expf(m - nm) + cs * __expf(cm - nm);
            m = nm;
            P += pP[o]; C += pC[o];
        }
        local += -(P / C - m - __logf(S));
    }
    #pragma unroll
    for (int mask = 1; mask < 64; mask <<= 1) local += __shfl_xor(local, mask);
    __shared__ float red[16];
    const int w = t >> 6, ln = t & 63;
    if (ln == 0) red[w] = local;
    __syncthreads();
    if (t < 16) {
        float v = red[t];
        #pragma unroll
        for (int mask = 1; mask < 16; mask <<= 1) v += __shfl_xor(v, mask, 16);
        if (t == 0) out[0] = v / (float)NTOT;
    }
}

extern "C" void kernel_launch(void* const* d_in, const int* in_sizes, int n_in,
                              void* d_out, int out_size, void* d_ws, size_t ws_size,
                              hipStream_t stream) {
    const float* feat = (const float*)d_in[0];
    const int* labels = (const int*)d_in[1];
    float* out = (float*)d_out;

    char* ws = (char*)d_ws;
    unsigned short* Bg = (unsigned short*)ws;                       // 4 MB
    int* labT = (int*)(ws + 4u * 1024u * 1024u);                    // 32 KB
    float* pM = (float*)(ws + 4u * 1024u * 1024u + 64u * 1024u);    // 8*8192 f32 each
    float* pS = pM + NCHUNK * NTOT;
    float* pP = pS + NCHUNK * NTOT;
    float* pC = pP + NCHUNK * NTOT;

    prep_kernel<<<NTOT, 64, 0, stream>>>(feat, labels, Bg, labT);
    dim3 grid(64, NCHUNK);
    supcon_main<<<grid, 256, 0, stream>>>(Bg, labT, pM, pS, pP, pC);
    finalize_kernel<<<1, 1024, 0, stream>>>(pM, pS, pP, pC, out);
}

// Round 2
// 91.943 us; speedup vs baseline: 1.2140x; 1.2140x over previous
//
#include <hip/hip_runtime.h>
#include <hip/hip_bf16.h>

#define NTOT 8192
#define NBSZ 4096
#define DDIM 256
#define NCHUNK 16
#define CHUNK_COLS 512
#define TILE_COLS 32
#define NCLASS 100

#define INV_T 14.285714285714286f
#define EPI_T 1.4285714285714286f
// base-2 folded constants: exp(logit) = exp2(dot*K1 + same*BIASS)
#define K1 20.609929155556076f      /* INV_T * log2(e) */
#define BIASS -2.0609929155556078f  /* -EPI_T * log2(e) */

typedef __attribute__((ext_vector_type(8))) __bf16 bf16x8;
typedef __attribute__((ext_vector_type(4))) float f32x4;

__device__ __forceinline__ unsigned short f2bf(float x) {
    union { float f; unsigned int u; } a; a.f = x;
    unsigned int r = a.u + 0x7fffu + ((a.u >> 16) & 1u);
    return (unsigned short)(r >> 16);
}
__device__ __forceinline__ float bf2f(unsigned short u) {
    union { unsigned int u; float f; } a; a.u = ((unsigned int)u) << 16;
    return a.f;
}

// K1: build bf16 contrast matrix B[8192][256] (view-major) + tiled labels.
__global__ __launch_bounds__(256) void prep_kernel(const float* __restrict__ feat,
                                                   const int* __restrict__ labels,
                                                   unsigned short* __restrict__ Bg,
                                                   int* __restrict__ labT) {
    const int g = blockIdx.x * 256 + threadIdx.x;   // 8192 rows x 64 lanes
    const int row = g >> 6, t = g & 63;
    const int v = row >> 12, b = row & (NBSZ - 1);
    const float* src = feat + (size_t)(b * 2 + v) * DDIM + t * 4;
    f32x4 val = *(const f32x4*)src;
    ushort4 o;
    o.x = f2bf(val[0]); o.y = f2bf(val[1]); o.z = f2bf(val[2]); o.w = f2bf(val[3]);
    *(ushort4*)(Bg + (size_t)row * DDIM + t * 4) = o;
    if (t == 0) labT[row] = labels[b];
}

// K2: per-class feature sums S[100][256] (fp32), deterministic compaction.
__global__ __launch_bounds__(256) void classsum_kernel(const unsigned short* __restrict__ Bg,
                                                       const int* __restrict__ labT,
                                                       float* __restrict__ S) {
    const int c = blockIdx.x, t = threadIdx.x;
    __shared__ int cnts[256];
    __shared__ short list[2048];
    __shared__ int tot_s;
    const int base = t * 32;
    int local = 0;
    for (int i = 0; i < 32; ++i) local += (labT[base + i] == c);
    cnts[t] = local;
    __syncthreads();
    int off = 0;
    for (int i = 0; i < t; ++i) off += cnts[i];
    for (int i = 0; i < 32; ++i)
        if (labT[base + i] == c) list[off++] = (short)(base + i);
    if (t == 255) tot_s = off;
    __syncthreads();
    const int tot = tot_s;
    float s = 0.f;
    for (int j = 0; j < tot; ++j)
        s += bf2f(Bg[(size_t)((unsigned short)list[j]) * DDIM + t]);
    S[c * DDIM + t] = s;
}

// K3: Gram + fused exp-sum. Grid (32 row-blocks, 16 col-chunks), 256 thr.
__global__ __launch_bounds__(256, 2) void supcon_main(
    const unsigned short* __restrict__ Bg, const int* __restrict__ labT,
    float* __restrict__ pS)
{
    __shared__ unsigned short btile[TILE_COLS * DDIM];  // 16 KB, 16B-chunk XOR swizzle
    __shared__ int labc_s[TILE_COLS];

    const int tid = threadIdx.x;
    const int wid = tid >> 6;
    const int lane = tid & 63;
    const int q = lane >> 4;
    const int r16 = lane & 15;

    const int rowBase = blockIdx.x * 256 + wid * 64;   // wave owns 64 rows
    const int colChunk = blockIdx.y * CHUNK_COLS;

    // A fragments: 64 rows x K=256 in registers (128 VGPR).
    bf16x8 afr[4][8];
    #pragma unroll
    for (int m = 0; m < 4; ++m) {
        const unsigned short* ap = Bg + (size_t)(rowBase + m * 16 + r16) * DDIM + q * 8;
        #pragma unroll
        for (int ks = 0; ks < 8; ++ks)
            afr[m][ks] = *(const bf16x8*)(ap + ks * 32);
    }
    int labrow[4][4];
    #pragma unroll
    for (int m = 0; m < 4; ++m)
        #pragma unroll
        for (int r = 0; r < 4; ++r)
            labrow[m][r] = labT[rowBase + m * 16 + q * 4 + r];

    float se[4][4];
    #pragma unroll
    for (int m = 0; m < 4; ++m)
        #pragma unroll
        for (int r = 0; r < 4; ++r) se[m][r] = 0.f;

    // prefetch tile 0
    bf16x8 pf[4];
    int pfl = 0;
    {
        const int colBase = colChunk;
        #pragma unroll
        for (int it = 0; it < 4; ++it) {
            int idx = it * 256 + tid;
            int brow = idx >> 5, bc = idx & 31;
            pf[it] = *(const bf16x8*)(Bg + (size_t)(colBase + brow) * DDIM + bc * 8);
        }
        if (tid < TILE_COLS) pfl = labT[colBase + tid];
    }

    for (int tile = 0; tile < CHUNK_COLS / TILE_COLS; ++tile) {
        const int colBase = colChunk + tile * TILE_COLS;
        __syncthreads();  // previous tile's readers done
        #pragma unroll
        for (int it = 0; it < 4; ++it) {
            int idx = it * 256 + tid;
            int brow = idx >> 5, bc = idx & 31;
            *(bf16x8*)(btile + brow * DDIM + (bc ^ (brow & 7)) * 8) = pf[it];
        }
        if (tid < TILE_COLS) labc_s[tid] = pfl;
        __syncthreads();

        // prefetch next tile (overlaps MFMA+epilogue below)
        if (tile + 1 < CHUNK_COLS / TILE_COLS) {
            const int nb = colChunk + (tile + 1) * TILE_COLS;
            #pragma unroll
            for (int it = 0; it < 4; ++it) {
                int idx = it * 256 + tid;
                int brow = idx >> 5, bc = idx & 31;
                pf[it] = *(const bf16x8*)(Bg + (size_t)(nb + brow) * DDIM + bc * 8);
            }
            if (tid < TILE_COLS) pfl = labT[nb + tid];
        }

        f32x4 acc[4][2];
        #pragma unroll
        for (int m = 0; m < 4; ++m) { acc[m][0] = (f32x4)0.f; acc[m][1] = (f32x4)0.f; }

        #pragma unroll
        for (int ks = 0; ks < 8; ++ks) {
            bf16x8 bq0, bq1;
            {
                int brow = r16;
                bq0 = *(const bf16x8*)(btile + brow * DDIM + (((ks * 4 + q) ^ (brow & 7)) * 8));
            }
            {
                int brow = 16 + r16;
                bq1 = *(const bf16x8*)(btile + brow * DDIM + (((ks * 4 + q) ^ (brow & 7)) * 8));
            }
            #pragma unroll
            for (int m = 0; m < 4; ++m) {
                acc[m][0] = __builtin_amdgcn_mfma_f32_16x16x32_bf16(afr[m][ks], bq0, acc[m][0], 0, 0, 0);
                acc[m][1] = __builtin_amdgcn_mfma_f32_16x16x32_bf16(afr[m][ks], bq1, acc[m][1], 0, 0, 0);
            }
        }

        // epilogue: se += exp2(acc*K1 + same*BIASS), diag zeroed (wave-uniform branch)
        const bool diagT = (unsigned)(colBase - rowBase) < 64u;
        if (!diagT) {
            #pragma unroll
            for (int n = 0; n < 2; ++n) {
                const int lc = labc_s[n * 16 + r16];
                #pragma unroll
                for (int m = 0; m < 4; ++m)
                    #pragma unroll
                    for (int r = 0; r < 4; ++r) {
                        float t = fmaf(acc[m][n][r], K1, (lc == labrow[m][r]) ? BIASS : 0.f);
                        se[m][r] += __builtin_amdgcn_exp2f(t);
                    }
            }
        } else {
            #pragma unroll
            for (int n = 0; n < 2; ++n) {
                const int lc = labc_s[n * 16 + r16];
                const int gcol = colBase + n * 16 + r16;
                #pragma unroll
                for (int m = 0; m < 4; ++m)
                    #pragma unroll
                    for (int r = 0; r < 4; ++r) {
                        const int grow = rowBase + m * 16 + q * 4 + r;
                        float t = fmaf(acc[m][n][r], K1, (lc == labrow[m][r]) ? BIASS : 0.f);
                        float e = __builtin_amdgcn_exp2f(t);
                        se[m][r] += (grow == gcol) ? 0.f : e;
                    }
            }
        }
    }

    // merge the 16 lanes (r16 bits) sharing each row
    #pragma unroll
    for (int mask = 1; mask <= 8; mask <<= 1)
        #pragma unroll
        for (int m = 0; m < 4; ++m)
            #pragma unroll
            for (int r = 0; r < 4; ++r)
                se[m][r] += __shfl_xor(se[m][r], mask);
    if (r16 == 0) {
        #pragma unroll
        for (int m = 0; m < 4; ++m)
            #pragma unroll
            for (int r = 0; r < 4; ++r)
                pS[(size_t)blockIdx.y * NTOT + rowBase + m * 16 + q * 4 + r] = se[m][r];
    }
}

// K4: per-row loss. 32 blocks x 256 threads, one row per thread.
__global__ __launch_bounds__(256) void rowloss_kernel(
    const unsigned short* __restrict__ Bg, const int* __restrict__ labT,
    const float* __restrict__ S, const float* __restrict__ pS,
    float* __restrict__ lossv)
{
    __shared__ int hist[NCLASS];
    const int t = threadIdx.x;
    if (t < NCLASS) hist[t] = 0;
    __syncthreads();
    for (int i = t; i < NTOT; i += 256) atomicAdd(&hist[labT[i]], 1);
    __syncthreads();

    const int row = blockIdx.x * 256 + t;
    const int lab = labT[row];
    const float pc = (float)(hist[lab] - 1);

    float se = 0.f;
    #pragma unroll
    for (int ch = 0; ch < NCHUNK; ++ch) se += pS[(size_t)ch * NTOT + row];

    const unsigned short* ar = Bg + (size_t)row * DDIM;
    const float* sr = S + lab * DDIM;
    float d1 = 0.f, d2 = 0.f;
    #pragma unroll 4
    for (int i = 0; i < 32; ++i) {
        bf16x8 av = *(const bf16x8*)(ar + i * 8);
        f32x4 s0 = *(const f32x4*)(sr + i * 8);
        f32x4 s1 = *(const f32x4*)(sr + i * 8 + 4);
        #pragma unroll
        for (int j = 0; j < 4; ++j) {
            float a = (float)av[j];
            d1 = fmaf(a, s0[j], d1); d2 = fmaf(a, a, d2);
        }
        #pragma unroll
        for (int j = 0; j < 4; ++j) {
            float a = (float)av[4 + j];
            d1 = fmaf(a, s1[j], d1); d2 = fmaf(a, a, d2);
        }
    }
    const float psd = d1 - d2;  // exclude self
    lossv[row] = EPI_T + __logf(se) - INV_T * psd / pc;
}

// K5: scalar mean.
__global__ __launch_bounds__(256) void reduce_kernel(const float* __restrict__ lossv,
                                                     float* __restrict__ out) {
    const int t = threadIdx.x;
    float s = 0.f;
    for (int i = t; i < NTOT; i += 256) s += lossv[i];
    #pragma unroll
    for (int mask = 1; mask < 64; mask <<= 1) s += __shfl_xor(s, mask);
    __shared__ float red[4];
    if ((t & 63) == 0) red[t >> 6] = s;
    __syncthreads();
    if (t == 0) out[0] = (red[0] + red[1] + red[2] + red[3]) * (1.f / (float)NTOT);
}

extern "C" void kernel_launch(void* const* d_in, const int* in_sizes, int n_in,
                              void* d_out, int out_size, void* d_ws, size_t ws_size,
                              hipStream_t stream) {
    const float* feat = (const float*)d_in[0];
    const int* labels = (const int*)d_in[1];
    float* out = (float*)d_out;

    char* ws = (char*)d_ws;
    unsigned short* Bg = (unsigned short*)ws;                        // 4 MB
    int* labT = (int*)(ws + (4u << 20));                             // 32 KB
    float* S = (float*)(ws + (4u << 20) + (64u << 10));              // 100 KB
    float* pS = (float*)(ws + (4u << 20) + (192u << 10));            // 512 KB
    float* lossv = (float*)(ws + (4u << 20) + (704u << 10));         // 32 KB

    prep_kernel<<<2048, 256, 0, stream>>>(feat, labels, Bg, labT);
    classsum_kernel<<<NCLASS, 256, 0, stream>>>(Bg, labT, S);
    dim3 grid(32, NCHUNK);
    supcon_main<<<grid, 256, 0, stream>>>(Bg, labT, pS);
    rowloss_kernel<<<32, 256, 0, stream>>>(Bg, labT, S, pS, lossv);
    reduce_kernel<<<1, 256, 0, stream>>>(lossv, out);
}

// Round 3
// 63.971 us; speedup vs baseline: 1.7448x; 1.4373x over previous
//
#include <hip/hip_runtime.h>
#include <hip/hip_bf16.h>

#define NTOT 8192
#define NBSZ 4096
#define DDIM 256
#define NCHUNK 16
#define CHUNK_COLS 512
#define TILE_COLS 32
#define NT (CHUNK_COLS / TILE_COLS)
#define NCLASS 100

#define INV_T 14.285714285714286f
#define EPI_T 1.4285714285714286f
// base-2 folded: exp(logit) = exp2(dot*K1 + same*BIASS)
#define K1 20.609929155556076f      /* INV_T * log2(e) */
#define BIASS -2.0609929155556078f  /* -EPI_T * log2(e) */

typedef __attribute__((ext_vector_type(8))) __bf16 bf16x8;
typedef __attribute__((ext_vector_type(4))) float f32x4;

__device__ __forceinline__ unsigned short f2bf(float x) {
    union { float f; unsigned int u; } a; a.f = x;
    unsigned int r = a.u + 0x7fffu + ((a.u >> 16) & 1u);
    return (unsigned short)(r >> 16);
}

// K1: build bf16 contrast matrix B[8192][256] (view-major) + tiled labels.
__global__ __launch_bounds__(256) void prep_kernel(const float* __restrict__ feat,
                                                   const int* __restrict__ labels,
                                                   unsigned short* __restrict__ Bg,
                                                   int* __restrict__ labT) {
    const int g = blockIdx.x * 256 + threadIdx.x;   // 8192 rows x 64 lanes
    const int row = g >> 6, t = g & 63;
    const int v = row >> 12, b = row & (NBSZ - 1);
    const float* src = feat + (size_t)(b * 2 + v) * DDIM + t * 4;
    f32x4 val = *(const f32x4*)src;
    ushort4 o;
    o.x = f2bf(val[0]); o.y = f2bf(val[1]); o.z = f2bf(val[2]); o.w = f2bf(val[3]);
    *(ushort4*)(Bg + (size_t)row * DDIM + t * 4) = o;
    if (t == 0) labT[row] = labels[b];
}

// DMA one 32x256 bf16 tile into LDS (linear dest, source pre-swizzled so the
// read-side XOR sees conflict-free layout). 4 x 16B per thread.
__device__ __forceinline__ void stage_tile(const unsigned short* __restrict__ Bg,
                                           unsigned short* buf, int colBase, int tid) {
    #pragma unroll
    for (int it = 0; it < 4; ++it) {
        int c = it * 256 + tid;          // 16B-chunk index, 0..1023
        int brow = c >> 5, bc = c & 31;
        int sc = bc ^ (brow & 7);        // inverse swizzle on SOURCE
        const unsigned short* src = Bg + (size_t)(colBase + brow) * DDIM + sc * 8;
        __builtin_amdgcn_global_load_lds(
            (const __attribute__((address_space(1))) void*)src,
            (__attribute__((address_space(3))) void*)(buf + (size_t)c * 8),
            16, 0, 0);
    }
}

// K2: Gram + fused exp-sum + positive-dot sum. Grid (32 row-blocks, 16 chunks).
__global__ __launch_bounds__(256, 2) void supcon_main(
    const unsigned short* __restrict__ Bg, const int* __restrict__ labT,
    float* __restrict__ pSe, float* __restrict__ pPd)
{
    __shared__ alignas(16) unsigned short btile[2][TILE_COLS * DDIM];  // 2 x 16 KB
    __shared__ int labc_s[CHUNK_COLS];                                 // 2 KB

    const int tid = threadIdx.x;
    const int wid = tid >> 6;
    const int lane = tid & 63;
    const int q = lane >> 4;
    const int r16 = lane & 15;

    const int rowBase = blockIdx.x * 256 + wid * 64;   // wave owns 64 rows
    const int colChunk = blockIdx.y * CHUNK_COLS;

    // stage this chunk's labels once
    labc_s[tid] = labT[colChunk + tid];
    labc_s[tid + 256] = labT[colChunk + 256 + tid];

    // A fragments: 64 rows x K=256 in registers (128 VGPR).
    bf16x8 afr[4][8];
    #pragma unroll
    for (int m = 0; m < 4; ++m) {
        const unsigned short* ap = Bg + (size_t)(rowBase + m * 16 + r16) * DDIM + q * 8;
        #pragma unroll
        for (int ks = 0; ks < 8; ++ks)
            afr[m][ks] = *(const bf16x8*)(ap + ks * 32);
    }
    int labrow[4][4];
    #pragma unroll
    for (int m = 0; m < 4; ++m)
        #pragma unroll
        for (int r = 0; r < 4; ++r)
            labrow[m][r] = labT[rowBase + m * 16 + q * 4 + r];

    float se[4][4], pd[4][4];
    #pragma unroll
    for (int m = 0; m < 4; ++m)
        #pragma unroll
        for (int r = 0; r < 4; ++r) { se[m][r] = 0.f; pd[m][r] = 0.f; }

    stage_tile(Bg, btile[0], colChunk, tid);
    __syncthreads();   // drains vmcnt -> tile 0 ready

    for (int tile = 0; tile < NT; ++tile) {
        // issue next tile's DMA before compute; stays in flight under MFMA
        if (tile + 1 < NT)
            stage_tile(Bg, btile[(tile + 1) & 1], colChunk + (tile + 1) * TILE_COLS, tid);

        const unsigned short* bt = btile[tile & 1];
        f32x4 acc[4][2];
        #pragma unroll
        for (int m = 0; m < 4; ++m) { acc[m][0] = (f32x4)0.f; acc[m][1] = (f32x4)0.f; }

        __builtin_amdgcn_s_setprio(1);
        #pragma unroll
        for (int ks = 0; ks < 8; ++ks) {
            const int cx = (ks * 4 + q) ^ (r16 & 7);
            bf16x8 bq0 = *(const bf16x8*)(bt + r16 * DDIM + cx * 8);
            bf16x8 bq1 = *(const bf16x8*)(bt + (16 + r16) * DDIM + cx * 8);
            #pragma unroll
            for (int m = 0; m < 4; ++m) {
                acc[m][0] = __builtin_amdgcn_mfma_f32_16x16x32_bf16(afr[m][ks], bq0, acc[m][0], 0, 0, 0);
                acc[m][1] = __builtin_amdgcn_mfma_f32_16x16x32_bf16(afr[m][ks], bq1, acc[m][1], 0, 0, 0);
            }
        }
        __builtin_amdgcn_s_setprio(0);

        const int colBase = colChunk + tile * TILE_COLS;
        const int lc0 = labc_s[tile * TILE_COLS + r16];
        const int lc1 = labc_s[tile * TILE_COLS + 16 + r16];
        const bool diagT = ((unsigned)(colBase - rowBase)) < 64u;
        if (!diagT) {
            #pragma unroll
            for (int n = 0; n < 2; ++n) {
                const int lc = n ? lc1 : lc0;
                #pragma unroll
                for (int m = 0; m < 4; ++m)
                    #pragma unroll
                    for (int r = 0; r < 4; ++r) {
                        const bool same = (lc == labrow[m][r]);
                        float a = acc[m][n][r];
                        float t = fmaf(a, K1, same ? BIASS : 0.f);
                        se[m][r] += __builtin_amdgcn_exp2f(t);
                        pd[m][r] += same ? a : 0.f;
                    }
            }
        } else {
            #pragma unroll
            for (int n = 0; n < 2; ++n) {
                const int lc = n ? lc1 : lc0;
                const int gcol = colBase + n * 16 + r16;
                #pragma unroll
                for (int m = 0; m < 4; ++m)
                    #pragma unroll
                    for (int r = 0; r < 4; ++r) {
                        const int grow = rowBase + m * 16 + q * 4 + r;
                        const bool same = (lc == labrow[m][r]);
                        const bool keep = (grow != gcol);
                        float a = acc[m][n][r];
                        float t = fmaf(a, K1, same ? BIASS : 0.f);
                        float e = __builtin_amdgcn_exp2f(t);
                        se[m][r] += keep ? e : 0.f;
                        pd[m][r] += (same && keep) ? a : 0.f;
                    }
            }
        }
        __syncthreads();   // drains DMA (next tile ready) + LDS reads done
    }

    // merge the 16 lanes (r16 bits) sharing each row
    #pragma unroll
    for (int mask = 1; mask <= 8; mask <<= 1)
        #pragma unroll
        for (int m = 0; m < 4; ++m)
            #pragma unroll
            for (int r = 0; r < 4; ++r) {
                se[m][r] += __shfl_xor(se[m][r], mask);
                pd[m][r] += __shfl_xor(pd[m][r], mask);
            }
    if (r16 == 0) {
        #pragma unroll
        for (int m = 0; m < 4; ++m) {
            const size_t o = (size_t)blockIdx.y * NTOT + rowBase + m * 16 + q * 4;
            f32x4 vs, vp;
            #pragma unroll
            for (int r = 0; r < 4; ++r) { vs[r] = se[m][r]; vp[r] = pd[m][r]; }
            *(f32x4*)(pSe + o) = vs;
            *(f32x4*)(pPd + o) = vp;
        }
    }
}

// K3: per-row loss + block partial sums. 32 blocks x 256 threads.
__global__ __launch_bounds__(256) void finalize_kernel(
    const int* __restrict__ labT, const float* __restrict__ pSe,
    const float* __restrict__ pPd, float* __restrict__ partial)
{
    __shared__ int hist[NCLASS];
    const int t = threadIdx.x;
    if (t < NCLASS) hist[t] = 0;
    __syncthreads();
    #pragma unroll
    for (int i = 0; i < NTOT / 256; ++i)
        atomicAdd(&hist[labT[i * 256 + t]], 1);   // coalesced label reads
    __syncthreads();

    const int row = blockIdx.x * 256 + t;
    const int lab = labT[row];
    float se = 0.f, pd = 0.f;
    #pragma unroll
    for (int ch = 0; ch < NCHUNK; ++ch) {
        se += pSe[(size_t)ch * NTOT + row];
        pd += pPd[(size_t)ch * NTOT + row];
    }
    const float pc = (float)(hist[lab] - 1);
    float loss = EPI_T + __logf(se) - INV_T * pd / pc;

    #pragma unroll
    for (int mask = 1; mask < 64; mask <<= 1) loss += __shfl_xor(loss, mask);
    __shared__ float red[4];
    if ((t & 63) == 0) red[t >> 6] = loss;
    __syncthreads();
    if (t == 0) partial[blockIdx.x] = red[0] + red[1] + red[2] + red[3];
}

// K4: final scalar.
__global__ __launch_bounds__(64) void final_reduce(const float* __restrict__ partial,
                                                   float* __restrict__ out) {
    const int t = threadIdx.x;
    float s = (t < 32) ? partial[t] : 0.f;
    #pragma unroll
    for (int mask = 1; mask < 64; mask <<= 1) s += __shfl_xor(s, mask);
    if (t == 0) out[0] = s * (1.f / (float)NTOT);
}

extern "C" void kernel_launch(void* const* d_in, const int* in_sizes, int n_in,
                              void* d_out, int out_size, void* d_ws, size_t ws_size,
                              hipStream_t stream) {
    const float* feat = (const float*)d_in[0];
    const int* labels = (const int*)d_in[1];
    float* out = (float*)d_out;

    char* ws = (char*)d_ws;
    unsigned short* Bg = (unsigned short*)ws;                        // 4 MB
    int* labT = (int*)(ws + (4u << 20));                             // 32 KB
    float* pSe = (float*)(ws + (4u << 20) + (64u << 10));            // 512 KB
    float* pPd = (float*)(ws + (4u << 20) + (576u << 10));           // 512 KB
    float* partial = (float*)(ws + (4u << 20) + (1088u << 10));      // 128 B

    prep_kernel<<<2048, 256, 0, stream>>>(feat, labels, Bg, labT);
    dim3 grid(32, NCHUNK);
    supcon_main<<<grid, 256, 0, stream>>>(Bg, labT, pSe, pPd);
    finalize_kernel<<<32, 256, 0, stream>>>(labT, pSe, pPd, partial);
    final_reduce<<<1, 64, 0, stream>>>(partial, out);
}